// Round 5
// baseline (135.996 us; speedup 1.0000x reference)
//
#include <hip/hip_runtime.h>
#include <stdint.h>

#define L_COORD 5.0f
#define L_NOOBJ 0.5f

#define BLOCK 256
#define CPB   256                          // cells per block (one chunk per block)
#define CHUNK_FLOATS (CPB * 30)            // 7680 floats = 30720 B per tensor

// Per-cell loss terms; p/t must be compile-time-indexed register arrays.
__device__ __forceinline__ void cell_terms(const float* __restrict__ p,
                                           const float* __restrict__ t,
                                           float& loc, float& cobj, float& cnoobj,
                                           float& clsn, float& nobj)
{
    float objf = (t[4] == 1.0f) ? 1.0f : 0.0f;
    float noobjf = 1.0f - objf;

    // IoU of both predicted boxes vs target box
    float tx1 = t[0] - t[2] * 0.5f, ty1 = t[1] - t[3] * 0.5f;
    float tx2 = t[0] + t[2] * 0.5f, ty2 = t[1] + t[3] * 0.5f;
    float tarea = t[2] * t[3];

    float a0x1 = p[0] - p[2] * 0.5f, a0y1 = p[1] - p[3] * 0.5f;
    float a0x2 = p[0] + p[2] * 0.5f, a0y2 = p[1] + p[3] * 0.5f;
    float iw0 = fmaxf(fminf(a0x2, tx2) - fmaxf(a0x1, tx1), 0.0f);
    float ih0 = fmaxf(fminf(a0y2, ty2) - fmaxf(a0y1, ty1), 0.0f);
    float in0 = iw0 * ih0;
    float iou0 = in0 / fmaxf(p[2] * p[3] + tarea - in0, 1e-10f);

    float a1x1 = p[5] - p[7] * 0.5f, a1y1 = p[6] - p[8] * 0.5f;
    float a1x2 = p[5] + p[7] * 0.5f, a1y2 = p[6] + p[8] * 0.5f;
    float iw1 = fmaxf(fminf(a1x2, tx2) - fmaxf(a1x1, tx1), 0.0f);
    float ih1 = fmaxf(fminf(a1y2, ty2) - fmaxf(a1y1, ty1), 0.0f);
    float in1 = iw1 * ih1;
    float iou1 = in1 / fmaxf(p[7] * p[8] + tarea - in1, 1e-10f);

    bool b0 = iou0 > iou1;
    float wx  = b0 ? p[0] : p[5];
    float wy  = b0 ? p[1] : p[6];
    float ww  = b0 ? p[2] : p[7];
    float whh = b0 ? p[3] : p[8];
    float wc  = b0 ? p[4] : p[9];
    float wiou = fmaxf(iou0, iou1);

    float dx = wx - t[0], dy = wy - t[1];
    float xy = dx * dx + dy * dy;
    float dw = sqrtf(ww) - sqrtf(t[2]);
    float dh = sqrtf(whh) - sqrtf(t[3]);
    float wh = dw * dw + dh * dh;
    loc += (xy + wh) * objf;

    float dc = wc - wiou;
    cobj += dc * dc * objf;

    // class CE: log_softmax over p[10..30) at argmax(target[10..30))
    float m = p[10];
#pragma unroll
    for (int k = 11; k < 30; ++k) m = fmaxf(m, p[k]);
    float s = 0.0f;
#pragma unroll
    for (int k = 10; k < 30; ++k) s += __expf(p[k] - m);

    float tm = t[10];
    float psel = p[10];
#pragma unroll
    for (int k = 11; k < 30; ++k) {
        bool gt = t[k] > tm;               // first-max wins (strict >)
        tm = gt ? t[k] : tm;
        psel = gt ? p[k] : psel;
    }
    float ce = (m + __logf(s)) - psel;
    clsn += ce * objf;
    nobj += objf;

    float d4 = p[4] - t[4], d9 = p[9] - t[9];
    cnoobj += (d4 * d4 + d9 * d9) * noobjf;
}

__global__ __launch_bounds__(BLOCK) void yolo_loss_fused(
    const float* __restrict__ pred, const float* __restrict__ target,
    float* __restrict__ partial,           // SoA: partial[comp * G + bid]
    unsigned int* __restrict__ counter,    // zeroed each launch
    float* __restrict__ out, float invB)
{
    __shared__ float smp[CHUNK_FLOATS];
    __shared__ float smt[CHUNK_FLOATS];

    const int wid  = threadIdx.x >> 6;
    const int lane = threadIdx.x & 63;
    const int G    = gridDim.x;            // == nchunks, one chunk per block
    const int b    = blockIdx.x;

    // ---- async global -> LDS staging, 1 KiB per instruction (m97 pattern) ----
    const size_t fbase = (size_t)b * CHUNK_FLOATS;
    for (int c = wid; c < 30; c += 4) {
        const float* gp = pred   + fbase + c * 256 + lane * 4;
        const float* gt = target + fbase + c * 256 + lane * 4;
        __builtin_amdgcn_global_load_lds(
            (const __attribute__((address_space(1))) void*)gp,
            (__attribute__((address_space(3))) void*)&smp[c * 256], 16, 0, 0);
        __builtin_amdgcn_global_load_lds(
            (const __attribute__((address_space(1))) void*)gt,
            (__attribute__((address_space(3))) void*)&smt[c * 256], 16, 0, 0);
    }
    asm volatile("s_waitcnt vmcnt(0)" ::: "memory");
    __syncthreads();

    float loc = 0.0f, cobj = 0.0f, cnoobj = 0.0f, clsn = 0.0f, nobj = 0.0f;

    // ---- per-cell math, one cell per thread, all compile-time indices ----
    {
        const float2* p2 = reinterpret_cast<const float2*>(&smp[threadIdx.x * 30]);
        const float2* t2 = reinterpret_cast<const float2*>(&smt[threadIdx.x * 30]);
        float p[30], t[30];
#pragma unroll
        for (int k = 0; k < 15; ++k) {
            float2 v = p2[k];
            p[2 * k] = v.x; p[2 * k + 1] = v.y;
        }
#pragma unroll
        for (int k = 0; k < 15; ++k) {
            float2 v = t2[k];
            t[2 * k] = v.x; t[2 * k + 1] = v.y;
        }
        cell_terms(p, t, loc, cobj, cnoobj, clsn, nobj);
    }

    // ---- block reduction: wave shuffle tree then cross-wave LDS ----
#pragma unroll
    for (int off = 32; off > 0; off >>= 1) {
        loc    += __shfl_down(loc, off);
        cobj   += __shfl_down(cobj, off);
        cnoobj += __shfl_down(cnoobj, off);
        clsn   += __shfl_down(clsn, off);
        nobj   += __shfl_down(nobj, off);
    }

    __shared__ float sm[4][5];
    __shared__ int amLast;
    if (lane == 0) {
        sm[wid][0] = loc; sm[wid][1] = cobj; sm[wid][2] = cnoobj;
        sm[wid][3] = clsn; sm[wid][4] = nobj;
    }
    __syncthreads();
    if (threadIdx.x == 0) {
        float a0 = 0.f, a1 = 0.f, a2 = 0.f, a3 = 0.f, a4 = 0.f;
#pragma unroll
        for (int w = 0; w < 4; ++w) {
            a0 += sm[w][0]; a1 += sm[w][1]; a2 += sm[w][2];
            a3 += sm[w][3]; a4 += sm[w][4];
        }
        partial[0 * G + b] = a0;
        partial[1 * G + b] = a1;
        partial[2 * G + b] = a2;
        partial[3 * G + b] = a3;
        partial[4 * G + b] = a4;
        __threadfence();                         // release: partials visible device-wide
        unsigned int old = atomicAdd(counter, 1u);   // device-scope (m20)
        amLast = (old == (unsigned int)(G - 1));
    }
    __syncthreads();

    // ---- last block reduces all partials (fixed order -> deterministic) ----
    if (amLast) {
        __threadfence();                         // acquire: invalidate stale L1/L2
        float v0 = 0.f, v1 = 0.f, v2 = 0.f, v3 = 0.f, v4 = 0.f;
        for (int i = threadIdx.x; i < G; i += BLOCK) {
            v0 += partial[0 * G + i];
            v1 += partial[1 * G + i];
            v2 += partial[2 * G + i];
            v3 += partial[3 * G + i];
            v4 += partial[4 * G + i];
        }
#pragma unroll
        for (int off = 32; off > 0; off >>= 1) {
            v0 += __shfl_down(v0, off);
            v1 += __shfl_down(v1, off);
            v2 += __shfl_down(v2, off);
            v3 += __shfl_down(v3, off);
            v4 += __shfl_down(v4, off);
        }
        __syncthreads();                         // sm[] reuse
        if (lane == 0) {
            sm[wid][0] = v0; sm[wid][1] = v1; sm[wid][2] = v2;
            sm[wid][3] = v3; sm[wid][4] = v4;
        }
        __syncthreads();
        if (threadIdx.x == 0) {
            float tl = 0.f, tc = 0.f, tn = 0.f, tcl = 0.f, tno = 0.f;
#pragma unroll
            for (int w = 0; w < 4; ++w) {
                tl += sm[w][0]; tc += sm[w][1]; tn += sm[w][2];
                tcl += sm[w][3]; tno += sm[w][4];
            }
            float nn = fmaxf(tno, 1.0f);
            float cls = tcl / nn;
            float total = (L_COORD * tl + tc + L_NOOBJ * tn + cls) * invB;
            out[0] = total;
            out[1] = tl;
            out[2] = tc;
            out[3] = tn;
            out[4] = cls;
        }
    }
}

extern "C" void kernel_launch(void* const* d_in, const int* in_sizes, int n_in,
                              void* d_out, int out_size, void* d_ws, size_t ws_size,
                              hipStream_t stream) {
    const float* pred = (const float*)d_in[0];
    const float* target = (const float*)d_in[1];
    float* out = (float*)d_out;

    // d_ws layout: [0..15] counter (16B, memset each launch), then partials SoA
    unsigned int* counter = (unsigned int*)d_ws;
    float* partial = (float*)d_ws + 4;

    int ncells = in_sizes[0] / 30;            // B*S*S = 802816
    int B = ncells / 49;                      // S = 7
    int nchunks = ncells / CPB;               // 3136 exact (802816 % 256 == 0)

    hipMemsetAsync(counter, 0, 16, stream);
    yolo_loss_fused<<<nchunks, BLOCK, 0, stream>>>(pred, target, partial, counter,
                                                   out, 1.0f / (float)B);
}

// Round 6
// 44.415 us; speedup vs baseline: 3.0620x; 3.0620x over previous
//
#include <hip/hip_runtime.h>
#include <stdint.h>

#define L_COORD 5.0f
#define L_NOOBJ 0.5f

#define BLOCK 128
#define CPB   128                          // cells per chunk (= threads per block)
#define CHUNK_FLOATS (CPB * 30)            // 3840 floats = 15360 B per tensor
#define KB_PER_TENSOR 15                   // 15 x 1KiB DMA pieces per tensor

// Per-cell loss terms; p/t must be compile-time-indexed register arrays.
__device__ __forceinline__ void cell_terms(const float* __restrict__ p,
                                           const float* __restrict__ t,
                                           float& loc, float& cobj, float& cnoobj,
                                           float& clsn, float& nobj)
{
    float objf = (t[4] == 1.0f) ? 1.0f : 0.0f;
    float noobjf = 1.0f - objf;

    // IoU of both predicted boxes vs target box
    float tx1 = t[0] - t[2] * 0.5f, ty1 = t[1] - t[3] * 0.5f;
    float tx2 = t[0] + t[2] * 0.5f, ty2 = t[1] + t[3] * 0.5f;
    float tarea = t[2] * t[3];

    float a0x1 = p[0] - p[2] * 0.5f, a0y1 = p[1] - p[3] * 0.5f;
    float a0x2 = p[0] + p[2] * 0.5f, a0y2 = p[1] + p[3] * 0.5f;
    float iw0 = fmaxf(fminf(a0x2, tx2) - fmaxf(a0x1, tx1), 0.0f);
    float ih0 = fmaxf(fminf(a0y2, ty2) - fmaxf(a0y1, ty1), 0.0f);
    float in0 = iw0 * ih0;
    float iou0 = in0 / fmaxf(p[2] * p[3] + tarea - in0, 1e-10f);

    float a1x1 = p[5] - p[7] * 0.5f, a1y1 = p[6] - p[8] * 0.5f;
    float a1x2 = p[5] + p[7] * 0.5f, a1y2 = p[6] + p[8] * 0.5f;
    float iw1 = fmaxf(fminf(a1x2, tx2) - fmaxf(a1x1, tx1), 0.0f);
    float ih1 = fmaxf(fminf(a1y2, ty2) - fmaxf(a1y1, ty1), 0.0f);
    float in1 = iw1 * ih1;
    float iou1 = in1 / fmaxf(p[7] * p[8] + tarea - in1, 1e-10f);

    bool b0 = iou0 > iou1;
    float wx  = b0 ? p[0] : p[5];
    float wy  = b0 ? p[1] : p[6];
    float ww  = b0 ? p[2] : p[7];
    float whh = b0 ? p[3] : p[8];
    float wc  = b0 ? p[4] : p[9];
    float wiou = fmaxf(iou0, iou1);

    float dx = wx - t[0], dy = wy - t[1];
    float xy = dx * dx + dy * dy;
    float dw = sqrtf(ww) - sqrtf(t[2]);
    float dh = sqrtf(whh) - sqrtf(t[3]);
    float wh = dw * dw + dh * dh;
    loc += (xy + wh) * objf;

    float dc = wc - wiou;
    cobj += dc * dc * objf;

    // class CE: log_softmax over p[10..30) at argmax(target[10..30))
    float m = p[10];
#pragma unroll
    for (int k = 11; k < 30; ++k) m = fmaxf(m, p[k]);
    float s = 0.0f;
#pragma unroll
    for (int k = 10; k < 30; ++k) s += __expf(p[k] - m);

    float tm = t[10];
    float psel = p[10];
#pragma unroll
    for (int k = 11; k < 30; ++k) {
        bool gt = t[k] > tm;               // first-max wins (strict >)
        tm = gt ? t[k] : tm;
        psel = gt ? p[k] : psel;
    }
    float ce = (m + __logf(s)) - psel;
    clsn += ce * objf;
    nobj += objf;

    float d4 = p[4] - t[4], d9 = p[9] - t[9];
    cnoobj += (d4 * d4 + d9 * d9) * noobjf;
}

__global__ __launch_bounds__(BLOCK) void yolo_loss_partial(
    const float* __restrict__ pred, const float* __restrict__ target,
    float* __restrict__ partial,           // SoA: partial[comp * gridDim.x + bid]
    int nchunks)
{
    __shared__ float smp[CHUNK_FLOATS];    // 15 KiB
    __shared__ float smt[CHUNK_FLOATS];    // 15 KiB

    const int wid  = threadIdx.x >> 6;     // 0..1
    const int lane = threadIdx.x & 63;

    float loc = 0.0f, cobj = 0.0f, cnoobj = 0.0f, clsn = 0.0f, nobj = 0.0f;

    // wave 0 stages pred, wave 1 stages target (15 x 1KiB each)
    const float* sbase = wid ? target : pred;
    float* dbase = wid ? smt : smp;

    for (int chunk = blockIdx.x; chunk < nchunks; chunk += gridDim.x) {
        const size_t fbase = (size_t)chunk * CHUNK_FLOATS;

        {
            const float* src = sbase + fbase + lane * 4;
#pragma unroll
            for (int c = 0; c < KB_PER_TENSOR; ++c)
                __builtin_amdgcn_global_load_lds(
                    (const __attribute__((address_space(1))) void*)(src + c * 256),
                    (__attribute__((address_space(3))) void*)(dbase + c * 256), 16, 0, 0);
        }
        asm volatile("s_waitcnt vmcnt(0)" ::: "memory");
        __syncthreads();

        // ---- per-cell math, one cell per thread, compile-time indices ----
        {
            const float2* p2 = reinterpret_cast<const float2*>(&smp[threadIdx.x * 30]);
            const float2* t2 = reinterpret_cast<const float2*>(&smt[threadIdx.x * 30]);
            float p[30], t[30];
#pragma unroll
            for (int k = 0; k < 15; ++k) {
                float2 v = p2[k];
                p[2 * k] = v.x; p[2 * k + 1] = v.y;
            }
#pragma unroll
            for (int k = 0; k < 15; ++k) {
                float2 v = t2[k];
                t[2 * k] = v.x; t[2 * k + 1] = v.y;
            }
            cell_terms(p, t, loc, cobj, cnoobj, clsn, nobj);
        }

        __syncthreads();                   // LDS reuse barrier before next staging
    }

    // ---- block reduction: wave shuffle tree then cross-wave LDS ----
#pragma unroll
    for (int off = 32; off > 0; off >>= 1) {
        loc    += __shfl_down(loc, off);
        cobj   += __shfl_down(cobj, off);
        cnoobj += __shfl_down(cnoobj, off);
        clsn   += __shfl_down(clsn, off);
        nobj   += __shfl_down(nobj, off);
    }

    __shared__ float sm[2][5];
    if (lane == 0) {
        sm[wid][0] = loc; sm[wid][1] = cobj; sm[wid][2] = cnoobj;
        sm[wid][3] = clsn; sm[wid][4] = nobj;
    }
    __syncthreads();
    if (threadIdx.x == 0) {
        int g = gridDim.x, b = blockIdx.x;
        partial[0 * g + b] = sm[0][0] + sm[1][0];
        partial[1 * g + b] = sm[0][1] + sm[1][1];
        partial[2 * g + b] = sm[0][2] + sm[1][2];
        partial[3 * g + b] = sm[0][3] + sm[1][3];
        partial[4 * g + b] = sm[0][4] + sm[1][4];
    }
}

__global__ __launch_bounds__(256) void yolo_reduce(
    const float* __restrict__ partial, int n, float* __restrict__ out, float invB)
{
    float v0 = 0.f, v1 = 0.f, v2 = 0.f, v3 = 0.f, v4 = 0.f;
    for (int i = threadIdx.x; i < n; i += 256) {
        v0 += partial[0 * n + i];
        v1 += partial[1 * n + i];
        v2 += partial[2 * n + i];
        v3 += partial[3 * n + i];
        v4 += partial[4 * n + i];
    }
#pragma unroll
    for (int off = 32; off > 0; off >>= 1) {
        v0 += __shfl_down(v0, off);
        v1 += __shfl_down(v1, off);
        v2 += __shfl_down(v2, off);
        v3 += __shfl_down(v3, off);
        v4 += __shfl_down(v4, off);
    }
    __shared__ float sm[4][5];
    int lane = threadIdx.x & 63;
    int wid = threadIdx.x >> 6;
    if (lane == 0) {
        sm[wid][0] = v0; sm[wid][1] = v1; sm[wid][2] = v2;
        sm[wid][3] = v3; sm[wid][4] = v4;
    }
    __syncthreads();
    if (threadIdx.x == 0) {
        float loc = 0.f, cobj = 0.f, cnoobj = 0.f, clsum = 0.f, nobj = 0.f;
#pragma unroll
        for (int w = 0; w < 4; ++w) {
            loc += sm[w][0]; cobj += sm[w][1]; cnoobj += sm[w][2];
            clsum += sm[w][3]; nobj += sm[w][4];
        }
        float nn = fmaxf(nobj, 1.0f);
        float cls = clsum / nn;
        float total = (L_COORD * loc + cobj + L_NOOBJ * cnoobj + cls) * invB;
        out[0] = total;
        out[1] = loc;
        out[2] = cobj;
        out[3] = cnoobj;
        out[4] = cls;
    }
}

extern "C" void kernel_launch(void* const* d_in, const int* in_sizes, int n_in,
                              void* d_out, int out_size, void* d_ws, size_t ws_size,
                              hipStream_t stream) {
    const float* pred = (const float*)d_in[0];
    const float* target = (const float*)d_in[1];
    float* out = (float*)d_out;
    float* partial = (float*)d_ws;

    int ncells = in_sizes[0] / 30;            // B*S*S = 802816 (divisible by 128)
    int B = ncells / 49;                      // S = 7
    int nchunks = ncells / CPB;               // 6272 exactly

    int blocks = nchunks;
    int maxb = (int)(ws_size / (5 * sizeof(float)));
    if (blocks > maxb) blocks = maxb;         // grid-stride covers the rest
    if (blocks < 1) blocks = 1;

    yolo_loss_partial<<<blocks, BLOCK, 0, stream>>>(pred, target, partial, nchunks);
    yolo_reduce<<<1, 256, 0, stream>>>(partial, blocks, out, 1.0f / (float)B);
}

// Round 7
// 38.344 us; speedup vs baseline: 3.5467x; 1.1583x over previous
//
#include <hip/hip_runtime.h>
#include <stdint.h>

#define L_COORD 5.0f
#define L_NOOBJ 0.5f

#define BLOCK 256
#define CPB   256                          // cells per chunk (= threads per block)
#define CHUNK_FLOATS (CPB * 30)            // 7680 floats = 30720 B per tensor
#define PERSIST_BLOCKS 512                 // 2 blocks/CU x 256 CUs

// Per-cell loss terms; p/t must be compile-time-indexed register arrays.
__device__ __forceinline__ void cell_terms(const float* __restrict__ p,
                                           const float* __restrict__ t,
                                           float& loc, float& cobj, float& cnoobj,
                                           float& clsn, float& nobj)
{
    float objf = (t[4] == 1.0f) ? 1.0f : 0.0f;
    float noobjf = 1.0f - objf;

    // IoU of both predicted boxes vs target box
    float tx1 = t[0] - t[2] * 0.5f, ty1 = t[1] - t[3] * 0.5f;
    float tx2 = t[0] + t[2] * 0.5f, ty2 = t[1] + t[3] * 0.5f;
    float tarea = t[2] * t[3];

    float a0x1 = p[0] - p[2] * 0.5f, a0y1 = p[1] - p[3] * 0.5f;
    float a0x2 = p[0] + p[2] * 0.5f, a0y2 = p[1] + p[3] * 0.5f;
    float iw0 = fmaxf(fminf(a0x2, tx2) - fmaxf(a0x1, tx1), 0.0f);
    float ih0 = fmaxf(fminf(a0y2, ty2) - fmaxf(a0y1, ty1), 0.0f);
    float in0 = iw0 * ih0;
    float iou0 = in0 / fmaxf(p[2] * p[3] + tarea - in0, 1e-10f);

    float a1x1 = p[5] - p[7] * 0.5f, a1y1 = p[6] - p[8] * 0.5f;
    float a1x2 = p[5] + p[7] * 0.5f, a1y2 = p[6] + p[8] * 0.5f;
    float iw1 = fmaxf(fminf(a1x2, tx2) - fmaxf(a1x1, tx1), 0.0f);
    float ih1 = fmaxf(fminf(a1y2, ty2) - fmaxf(a1y1, ty1), 0.0f);
    float in1 = iw1 * ih1;
    float iou1 = in1 / fmaxf(p[7] * p[8] + tarea - in1, 1e-10f);

    bool b0 = iou0 > iou1;
    float wx  = b0 ? p[0] : p[5];
    float wy  = b0 ? p[1] : p[6];
    float ww  = b0 ? p[2] : p[7];
    float whh = b0 ? p[3] : p[8];
    float wc  = b0 ? p[4] : p[9];
    float wiou = fmaxf(iou0, iou1);

    float dx = wx - t[0], dy = wy - t[1];
    float xy = dx * dx + dy * dy;
    float dw = sqrtf(ww) - sqrtf(t[2]);
    float dh = sqrtf(whh) - sqrtf(t[3]);
    float wh = dw * dw + dh * dh;
    loc += (xy + wh) * objf;

    float dc = wc - wiou;
    cobj += dc * dc * objf;

    // class CE: log_softmax over p[10..30) at argmax(target[10..30))
    float m = p[10];
#pragma unroll
    for (int k = 11; k < 30; ++k) m = fmaxf(m, p[k]);
    float s = 0.0f;
#pragma unroll
    for (int k = 10; k < 30; ++k) s += __expf(p[k] - m);

    float tm = t[10];
    float psel = p[10];
#pragma unroll
    for (int k = 11; k < 30; ++k) {
        bool gt = t[k] > tm;               // first-max wins (strict >)
        tm = gt ? t[k] : tm;
        psel = gt ? p[k] : psel;
    }
    float ce = (m + __logf(s)) - psel;
    clsn += ce * objf;
    nobj += objf;

    float d4 = p[4] - t[4], d9 = p[9] - t[9];
    cnoobj += (d4 * d4 + d9 * d9) * noobjf;
}

__global__ __launch_bounds__(BLOCK) void yolo_loss_partial(
    const float* __restrict__ pred, const float* __restrict__ target,
    float* __restrict__ partial,           // SoA: partial[comp * gridDim.x + bid]
    int nchunks)
{
    __shared__ float smp[CHUNK_FLOATS];    // 30 KiB
    __shared__ float smt[CHUNK_FLOATS];    // 30 KiB

    const int wid  = threadIdx.x >> 6;     // 0..3
    const int lane = threadIdx.x & 63;

    // staging geometry (R3-proven): waves 0,1 -> pred (pieces 0-14 / 15-29),
    // waves 2,3 -> target
    const float* sbase = (wid & 2) ? target : pred;
    float* dbase       = ((wid & 2) ? smt : smp) + (wid & 1) * 15 * 256;
    const int sub0     = (wid & 1) * 15;

    float loc = 0.0f, cobj = 0.0f, cnoobj = 0.0f, clsn = 0.0f, nobj = 0.0f;

    for (int chunk = blockIdx.x; chunk < nchunks; chunk += gridDim.x) {
        const float* src = sbase + (size_t)chunk * CHUNK_FLOATS + sub0 * 256 + lane * 4;
#pragma unroll
        for (int c = 0; c < 15; ++c)
            __builtin_amdgcn_global_load_lds(
                (const __attribute__((address_space(1))) void*)(src + c * 256),
                (__attribute__((address_space(3))) void*)(dbase + c * 256), 16, 0, 0);

        asm volatile("s_waitcnt vmcnt(0)" ::: "memory");
        __syncthreads();

        // ---- per-cell math, one cell per thread, compile-time indices ----
        {
            const float2* p2 = reinterpret_cast<const float2*>(&smp[threadIdx.x * 30]);
            const float2* t2 = reinterpret_cast<const float2*>(&smt[threadIdx.x * 30]);
            float p[30], t[30];
#pragma unroll
            for (int k = 0; k < 15; ++k) {
                float2 v = p2[k];
                p[2 * k] = v.x; p[2 * k + 1] = v.y;
            }
#pragma unroll
            for (int k = 0; k < 15; ++k) {
                float2 v = t2[k];
                t[2 * k] = v.x; t[2 * k + 1] = v.y;
            }
            cell_terms(p, t, loc, cobj, cnoobj, clsn, nobj);
        }

        __syncthreads();                   // LDS reuse barrier before next staging
    }

    // ---- block reduction (once per persistent block) ----
#pragma unroll
    for (int off = 32; off > 0; off >>= 1) {
        loc    += __shfl_down(loc, off);
        cobj   += __shfl_down(cobj, off);
        cnoobj += __shfl_down(cnoobj, off);
        clsn   += __shfl_down(clsn, off);
        nobj   += __shfl_down(nobj, off);
    }

    __shared__ float sm[4][5];
    if (lane == 0) {
        sm[wid][0] = loc; sm[wid][1] = cobj; sm[wid][2] = cnoobj;
        sm[wid][3] = clsn; sm[wid][4] = nobj;
    }
    __syncthreads();
    if (threadIdx.x == 0) {
        float a0 = 0.f, a1 = 0.f, a2 = 0.f, a3 = 0.f, a4 = 0.f;
#pragma unroll
        for (int w = 0; w < 4; ++w) {
            a0 += sm[w][0]; a1 += sm[w][1]; a2 += sm[w][2];
            a3 += sm[w][3]; a4 += sm[w][4];
        }
        int g = gridDim.x, b = blockIdx.x;
        partial[0 * g + b] = a0;
        partial[1 * g + b] = a1;
        partial[2 * g + b] = a2;
        partial[3 * g + b] = a3;
        partial[4 * g + b] = a4;
    }
}

__global__ __launch_bounds__(256) void yolo_reduce(
    const float* __restrict__ partial, int n, float* __restrict__ out, float invB)
{
    float v0 = 0.f, v1 = 0.f, v2 = 0.f, v3 = 0.f, v4 = 0.f;
    for (int i = threadIdx.x; i < n; i += 256) {
        v0 += partial[0 * n + i];
        v1 += partial[1 * n + i];
        v2 += partial[2 * n + i];
        v3 += partial[3 * n + i];
        v4 += partial[4 * n + i];
    }
#pragma unroll
    for (int off = 32; off > 0; off >>= 1) {
        v0 += __shfl_down(v0, off);
        v1 += __shfl_down(v1, off);
        v2 += __shfl_down(v2, off);
        v3 += __shfl_down(v3, off);
        v4 += __shfl_down(v4, off);
    }
    __shared__ float sm[4][5];
    int lane = threadIdx.x & 63;
    int wid = threadIdx.x >> 6;
    if (lane == 0) {
        sm[wid][0] = v0; sm[wid][1] = v1; sm[wid][2] = v2;
        sm[wid][3] = v3; sm[wid][4] = v4;
    }
    __syncthreads();
    if (threadIdx.x == 0) {
        float loc = 0.f, cobj = 0.f, cnoobj = 0.f, clsum = 0.f, nobj = 0.f;
#pragma unroll
        for (int w = 0; w < 4; ++w) {
            loc += sm[w][0]; cobj += sm[w][1]; cnoobj += sm[w][2];
            clsum += sm[w][3]; nobj += sm[w][4];
        }
        float nn = fmaxf(nobj, 1.0f);
        float cls = clsum / nn;
        float total = (L_COORD * loc + cobj + L_NOOBJ * cnoobj + cls) * invB;
        out[0] = total;
        out[1] = loc;
        out[2] = cobj;
        out[3] = cnoobj;
        out[4] = cls;
    }
}

extern "C" void kernel_launch(void* const* d_in, const int* in_sizes, int n_in,
                              void* d_out, int out_size, void* d_ws, size_t ws_size,
                              hipStream_t stream) {
    const float* pred = (const float*)d_in[0];
    const float* target = (const float*)d_in[1];
    float* out = (float*)d_out;
    float* partial = (float*)d_ws;

    int ncells = in_sizes[0] / 30;            // B*S*S = 802816 (divisible by 256)
    int B = ncells / 49;                      // S = 7
    int nchunks = ncells / CPB;               // 3136 exactly

    int blocks = nchunks < PERSIST_BLOCKS ? nchunks : PERSIST_BLOCKS;
    int maxb = (int)(ws_size / (5 * sizeof(float)));
    if (blocks > maxb) blocks = maxb;         // grid-stride covers the rest
    if (blocks < 1) blocks = 1;

    yolo_loss_partial<<<blocks, BLOCK, 0, stream>>>(pred, target, partial, nchunks);
    yolo_reduce<<<1, 256, 0, stream>>>(partial, blocks, out, 1.0f / (float)B);
}